// Round 22
// baseline (356.502 us; speedup 1.0000x reference)
//
#include <hip/hip_runtime.h>

typedef unsigned short u16;
typedef __bf16 bf16x8 __attribute__((ext_vector_type(8)));
typedef float f32x4 __attribute__((ext_vector_type(4)));
typedef float f32x16 __attribute__((ext_vector_type(16)));
typedef u16 u16x4 __attribute__((ext_vector_type(4)));
typedef unsigned int u32x4v __attribute__((ext_vector_type(4)));

#define LOG2E_OVER_8 0.18033688011112043f

__device__ __forceinline__ u16 f2bf(float f) {
  union { float f; unsigned int u; } x{f};
  unsigned int r = (x.u + 0x7fffu + ((x.u >> 16) & 1u)) >> 16;
  return (u16)r;
}

__device__ __forceinline__ float bf2f(u16 v) {
  union { unsigned int u; float f; } x;
  x.u = ((unsigned int)v) << 16;
  return x.f;
}

__device__ __forceinline__ unsigned cvtpk(float a, float b) {
  unsigned r;
  asm("v_cvt_pk_bf16_f32 %0, %1, %2" : "=v"(r) : "v"(a), "v"(b));
  return r;
}

__device__ __forceinline__ void gld16(const void* g, void* l) {
  __builtin_amdgcn_global_load_lds((const __attribute__((address_space(1))) unsigned int*)g,
                                   (__attribute__((address_space(3))) unsigned int*)l,
                                   16, 0, 0);
}

// ---------------- weight prep -------------------------------------------------
__global__ void prep_w(const float* __restrict__ Wq, const float* __restrict__ Wk,
                       const float* __restrict__ Wv, const float* __restrict__ Wg,
                       const float* __restrict__ Wb, const float* __restrict__ Wo,
                       u16* __restrict__ Wqt, u16* __restrict__ Wkt, u16* __restrict__ Wvt,
                       u16* __restrict__ Wcn, u16* __restrict__ Wot)
{
  __shared__ float tile[32][33];
  const int m = blockIdx.z;
  const int nb = blockIdx.x * 32, kb = blockIdx.y * 32;
  const int tx = threadIdx.x, ty = threadIdx.y;
  const float* src = (m == 0) ? Wq : (m == 1) ? Wk : (m == 2) ? Wv : (m == 3) ? Wg : Wo;
  u16* dst = (m == 0) ? Wqt : (m == 1) ? Wkt : (m == 2) ? Wvt : (m == 3) ? Wcn : Wot;
#pragma unroll
  for (int i = 0; i < 4; ++i) {
    const int k = kb + ty + i * 8;
    float v = src[k * 1024 + nb + tx];
    if (m == 3) v = 8.0f * v + Wb[k * 1024 + nb + tx];
    if (m == 0) v *= LOG2E_OVER_8;
    if (m == 3) dst[k * 1024 + nb + tx] = f2bf(v);   // direct, non-transposed
    else        tile[ty + i * 8][tx] = v;
  }
  __syncthreads();
  if (m != 3) {
#pragma unroll
    for (int i = 0; i < 4; ++i) {
      const int r = ty + i * 8;
      dst[(nb + r) * 1024 + kb + tx] = f2bf(tile[tx][r]);
    }
  }
}

__global__ void prep_b(const float* __restrict__ bq, const float* __restrict__ bg,
                       const float* __restrict__ bb,
                       float* __restrict__ bqs, float* __restrict__ bcs)
{
  const int i = blockIdx.x * 256 + threadIdx.x;
  if (i < 1024) {
    bqs[i] = bq[i] * LOG2E_OVER_8;
    bcs[i] = 8.0f * bg[i] + bb[i];
  }
}

// ---------------- f32 -> bf16 convert (both tensors, one dispatch) -----------
__global__ void cvt2_bf16(const float* __restrict__ in0, u16* __restrict__ out0,
                          const float* __restrict__ in1, u16* __restrict__ out1, int n)
{
  int i = (blockIdx.x * blockDim.x + threadIdx.x) * 4;
  const int stride = gridDim.x * blockDim.x * 4;
  for (; i < n; i += stride) {
    const float4 v0 = *reinterpret_cast<const float4*>(in0 + i);
    u16x4 o0;
    o0.x = f2bf(v0.x); o0.y = f2bf(v0.y); o0.z = f2bf(v0.z); o0.w = f2bf(v0.w);
    *reinterpret_cast<u16x4*>(out0 + i) = o0;
    const float4 v1 = *reinterpret_cast<const float4*>(in1 + i);
    u16x4 o1;
    o1.x = f2bf(v1.x); o1.y = f2bf(v1.y); o1.z = f2bf(v1.z); o1.w = f2bf(v1.w);
    *reinterpret_cast<u16x4*>(out1 + i) = o1;
  }
}

// ---------------- GEMM body (round-14 verified single-buffer, BK=64) ----------
// XOR-swizzled LDS (G21 both-sides, SQ_LDS_BANK_CONFLICT=0 verified).
// EPI: 0 = bf16 out; 1 = fp32 + bf16 out; 2 = bf16 out transposed per head
//      Vt[b][h][d][s]; 3 = fp32 out only; 4 = bf16 out, NO bias.
template<int EPI, int NB>
__device__ __forceinline__ void gemm_body(int bid0, u16* lA, u16* lB,
                                          const u16* __restrict__ A,
                                          const u16* __restrict__ Bt,
                                          const float* __restrict__ bias,
                                          u16* __restrict__ outb, float* __restrict__ outf)
{
  int bid = (bid0 & 7) * NB + (bid0 >> 3);   // XCD-contiguous row bands (grid%8==0)
  const int row0 = (bid >> 3) * 128;
  const int col0 = (bid & 7) * 128;
  const int t = threadIdx.x;
  const int w = t >> 6, lane = t & 63;
  const int l15 = lane & 15, l4 = lane >> 4;
  const int wr = w >> 1, wc = w & 1;
  const int l7 = l15 & 7;

  const u16* gA[4];
  const u16* gB[4];
#pragma unroll
  for (int k2 = 0; k2 < 4; ++k2) {
    const int c = k2 * 256 + t;
    const int r = c >> 3;
    const int sc = ((c & 7) ^ (r & 7)) * 8;
    gA[k2] = A + (row0 + r) * 1024 + sc;
    gB[k2] = Bt + (col0 + r) * 1024 + sc;
  }

  f32x4 acc[4][4] = {};

  for (int kt = 0; kt < 1024; kt += 64) {
#pragma unroll
    for (int k2 = 0; k2 < 4; ++k2) {
      gld16(gA[k2] + kt, lA + (k2 * 256 + w * 64) * 8);
      gld16(gB[k2] + kt, lB + (k2 * 256 + w * 64) * 8);
    }
    __syncthreads();
    bf16x8 aF[4][2], bF[4][2];
#pragma unroll
    for (int m = 0; m < 4; ++m)
#pragma unroll
      for (int ks = 0; ks < 2; ++ks)
        aF[m][ks] = *reinterpret_cast<const bf16x8*>(
            &lA[(wr * 64 + m * 16 + l15) * 64 + ((ks * 4 + l4) ^ l7) * 8]);
#pragma unroll
    for (int n = 0; n < 4; ++n)
#pragma unroll
      for (int ks = 0; ks < 2; ++ks)
        bF[n][ks] = *reinterpret_cast<const bf16x8*>(
            &lB[(wc * 64 + n * 16 + l15) * 64 + ((ks * 4 + l4) ^ l7) * 8]);
#pragma unroll
    for (int m = 0; m < 4; ++m)
#pragma unroll
      for (int n = 0; n < 4; ++n) {
        acc[m][n] = __builtin_amdgcn_mfma_f32_16x16x32_bf16(aF[m][0], bF[n][0], acc[m][n], 0, 0, 0);
        acc[m][n] = __builtin_amdgcn_mfma_f32_16x16x32_bf16(aF[m][1], bF[n][1], acc[m][n], 0, 0, 0);
      }
    __syncthreads();
  }

  float bv[4];
#pragma unroll
  for (int n = 0; n < 4; ++n)
    bv[n] = (EPI == 4) ? 0.0f : bias[col0 + wc * 64 + n * 16 + l15];
#pragma unroll
  for (int m = 0; m < 4; ++m) {
#pragma unroll
    for (int n = 0; n < 4; ++n) {
      const int c = col0 + wc * 64 + n * 16 + l15;
#pragma unroll
      for (int j = 0; j < 4; ++j) {
        const int r = row0 + wr * 64 + m * 16 + l4 * 4 + j;
        const float v = acc[m][n][j] + bv[n];
        if constexpr (EPI == 0 || EPI == 4) {
          outb[r * 1024 + c] = f2bf(v);
        } else if constexpr (EPI == 1) {
          outf[r * 1024 + c] = v;
          outb[r * 1024 + c] = f2bf(v);
        } else if constexpr (EPI == 2) {
          const int bi = r >> 10, s = r & 1023;
          const int h = c >> 6, d = c & 63;
          outb[((bi * 16 + h) * 64 + d) * 1024 + s] = f2bf(v);
        } else {
          outf[r * 1024 + c] = v;
        }
      }
    }
  }
}

// bias job: bco[n] = dot(bcs, Wot-row-n) + bo[n]; 256 blocks, wave per row
__device__ __forceinline__ void bias_body(int bb, const float* __restrict__ bcs,
                                          const u16* __restrict__ Wot,
                                          const float* __restrict__ bo,
                                          float* __restrict__ bco)
{
  const int t = threadIdx.x, w = t >> 6, l = t & 63;
  const int n = bb * 4 + w;
  const u16* row = Wot + n * 1024;
  float a = 0.f;
#pragma unroll
  for (int i = 0; i < 16; ++i) a += bcs[l + 64 * i] * bf2f(row[l + 64 * i]);
#pragma unroll
  for (int d = 1; d < 64; d <<= 1) a += __shfl_xor(a, d);
  if (l == 0) bco[n] = a + bo[n];
}

template<int EPI, int NB = 64>
__global__ __launch_bounds__(256, 2)
void gemm_k(const u16* __restrict__ A, const u16* __restrict__ Bt,
            const float* __restrict__ bias,
            u16* __restrict__ outb, float* __restrict__ outf)
{
  __shared__ u16 lA[128 * 64];
  __shared__ u16 lB[128 * 64];
  gemm_body<EPI, NB>((int)blockIdx.x, lA, lB, A, Bt, bias, outb, outf);
}

// pass-1 mega: Q1(0-511), K1(512-1023), V1(1024-1535), Wcot(1536-1599),
// bias_dot(1600-1855). grid = 1856.
__global__ __launch_bounds__(256, 2)
void gemmp1_k(const u16* __restrict__ Xb, const u16* __restrict__ Yb,
              const u16* __restrict__ Wqt, const float* __restrict__ bqs,
              const u16* __restrict__ Wkt, const float* __restrict__ bk,
              const u16* __restrict__ Wvt, const float* __restrict__ bv,
              u16* __restrict__ Qb, u16* __restrict__ Kb, u16* __restrict__ Vt,
              const u16* __restrict__ Wot, const u16* __restrict__ Wcn,
              u16* __restrict__ Wcot,
              const float* __restrict__ bcs, const float* __restrict__ bo,
              float* __restrict__ bco)
{
  __shared__ u16 lA[128 * 64];
  __shared__ u16 lB[128 * 64];
  const int id = (int)blockIdx.x;
  if (id < 512)       gemm_body<0, 64>(id,        lA, lB, Xb, Wqt, bqs, Qb, nullptr);
  else if (id < 1024) gemm_body<0, 64>(id - 512,  lA, lB, Yb, Wkt, bk, Kb, nullptr);
  else if (id < 1536) gemm_body<2, 64>(id - 1024, lA, lB, Yb, Wvt, bv, Vt, nullptr);
  else if (id < 1600) gemm_body<4, 8>(id - 1536,  lA, lB, Wot, Wcn, nullptr, Wcot, nullptr);
  else                bias_body(id - 1600, bcs, Wot, bo, bco);
}

// pass-2: Q2(0-511), K2(512-1023), V2(1024-1535). grid = 1536.
// K2/V2 stay adjacent to attn2 (producer->consumer L2 warmth is load-bearing:
// hoisting them earlier cost ~20us of cold HBM reads in attn2, round 21).
__global__ __launch_bounds__(256, 2)
void gemmp2_k(const u16* __restrict__ A0, const u16* __restrict__ B0,
              const float* __restrict__ c0, u16* __restrict__ o0,
              const u16* __restrict__ A1, const u16* __restrict__ B1,
              const float* __restrict__ c1, u16* __restrict__ o1,
              const u16* __restrict__ A2, const u16* __restrict__ B2,
              const float* __restrict__ c2, u16* __restrict__ o2)
{
  __shared__ u16 lA[128 * 64];
  __shared__ u16 lB[128 * 64];
  const int id = (int)blockIdx.x;
  if (id < 512)       gemm_body<0, 64>(id,        lA, lB, A0, B0, c0, o0, nullptr);
  else if (id < 1024) gemm_body<0, 64>(id - 512,  lA, lB, A1, B1, c1, o1, nullptr);
  else                gemm_body<2, 64>(id - 1024, lA, lB, A2, B2, c2, o2, nullptr);
}

// ---------------- flash attention v8: KVBLK=128 --------------------------------
// Same v7 math (no-max softmax, permlane32_swap, swapped-QK^T 32x32x16) but
// kv tiles of 128: HALVES the barrier/stage points (16 vs 32) and doubles the
// prefetch window. K tile [128 kv][72] (proven stride); V^T as TWO [64 d][72]
// slabs (one per 64-s half) so the verified conflict-free pattern is kept.
// LDS 36.9KB x 4 blocks/CU = 147 <= 160; VGPR ~105 <= 128 for (256,4).
__global__ __launch_bounds__(256, 4)
void attn_k(const u16* __restrict__ Q, const u16* __restrict__ K,
            const u16* __restrict__ Vt, u16* __restrict__ ctx)
{
  __shared__ u16 lK[128 * 72];
  __shared__ u16 lV[2][64 * 72];
  __shared__ float lsumI[4][32];
  const int id = (int)blockIdx.x;
  const int xcd = id & 7, o = id >> 3;
  const int pair = xcd * 16 + (o >> 3);   // 16 (b,h) pairs per XCD
  const int qt = o & 7;
  const int b = pair >> 4, h = pair & 15;
  const int t = threadIdx.x, w = t >> 6, lane = t & 63;
  const int l31 = lane & 31, hi = lane >> 5;
  const int q0 = qt * 128 + w * 32;
  const u16* Qp = Q + (size_t)b * (1024 * 1024) + h * 64;
  const u16* Kp = K + (size_t)b * (1024 * 1024) + h * 64;
  const u16* Vp = Vt + (size_t)(b * 16 + h) * (64 * 1024);

  // staging: thread t owns K rows r0+32i (i=0..3) chunk c0; V rows r0,r0+32
  // in each of the two 64-s slabs.
  const int r0 = t >> 3, c0 = (t & 7) * 8;

  bf16x8 bQ[4];
#pragma unroll
  for (int ks = 0; ks < 4; ++ks)
    bQ[ks] = *reinterpret_cast<const bf16x8*>(&Qp[(q0 + l31) * 1024 + ks * 16 + hi * 8]);

  f32x16 acc[2] = {};
  float lsum = 0.f;

  bf16x8 sK[4], sV[4];
#pragma unroll
  for (int i = 0; i < 4; ++i)
    sK[i] = *reinterpret_cast<const bf16x8*>(&Kp[(r0 + 32 * i) * 1024 + c0]);
#pragma unroll
  for (int j = 0; j < 2; ++j)
#pragma unroll
    for (int i = 0; i < 2; ++i)
      sV[j * 2 + i] = *reinterpret_cast<const bf16x8*>(
          &Vp[(r0 + 32 * i) * 1024 + j * 64 + c0]);

  for (int it = 0; it < 8; ++it) {
    const int kv0 = it * 128;
    __syncthreads();   // all waves done reading previous tile
#pragma unroll
    for (int i = 0; i < 4; ++i)
      *reinterpret_cast<bf16x8*>(&lK[(r0 + 32 * i) * 72 + c0]) = sK[i];
#pragma unroll
    for (int j = 0; j < 2; ++j)
#pragma unroll
      for (int i = 0; i < 2; ++i)
        *reinterpret_cast<bf16x8*>(&lV[j][(r0 + 32 * i) * 72 + c0]) = sV[j * 2 + i];
    __syncthreads();   // tile ready
    if (it + 1 < 8) {  // issue next tile: in flight across 2 compute halves
      const int nk = kv0 + 128;
#pragma unroll
      for (int i = 0; i < 4; ++i)
        sK[i] = *reinterpret_cast<const bf16x8*>(&Kp[(nk + r0 + 32 * i) * 1024 + c0]);
#pragma unroll
      for (int j = 0; j < 2; ++j)
#pragma unroll
        for (int i = 0; i < 2; ++i)
          sV[j * 2 + i] = *reinterpret_cast<const bf16x8*>(
              &Vp[(r0 + 32 * i) * 1024 + nk + j * 64 + c0]);
    }

#pragma unroll
    for (int half = 0; half < 2; ++half) {
      // S^T = K Q^T for this 64-kv half: 2 sub-tiles of 32
      f32x16 sS[2] = {};
      __builtin_amdgcn_s_setprio(1);
#pragma unroll
      for (int tt = 0; tt < 2; ++tt) {
#pragma unroll
        for (int ks = 0; ks < 4; ++ks) {
          const bf16x8 aK = *reinterpret_cast<const bf16x8*>(
              &lK[(half * 64 + tt * 32 + l31) * 72 + ks * 16 + hi * 8]);
          sS[tt] = __builtin_amdgcn_mfma_f32_32x32x16_bf16(aK, bQ[ks], sS[tt], 0, 0, 0);
        }
      }
      __builtin_amdgcn_s_setprio(0);

      // P = exp2(S); pack bf16 pairs; permlane32_swap -> PV A-frags
      unsigned pa[2][2][4];
#pragma unroll
      for (int tt = 0; tt < 2; ++tt) {
        float p[16];
        float s0 = 0.f, s1 = 0.f, s2 = 0.f, s3 = 0.f;
#pragma unroll
        for (int r = 0; r < 16; r += 4) {
          p[r]     = __builtin_amdgcn_exp2f(sS[tt][r]);
          p[r + 1] = __builtin_amdgcn_exp2f(sS[tt][r + 1]);
          p[r + 2] = __builtin_amdgcn_exp2f(sS[tt][r + 2]);
          p[r + 3] = __builtin_amdgcn_exp2f(sS[tt][r + 3]);
          s0 += p[r]; s1 += p[r + 1]; s2 += p[r + 2]; s3 += p[r + 3];
        }
        lsum += (s0 + s1) + (s2 + s3);
        unsigned wv[8];
#pragma unroll
        for (int i = 0; i < 8; ++i) wv[i] = cvtpk(p[2 * i], p[2 * i + 1]);
#pragma unroll
        for (int c = 0; c < 2; ++c) {
          unsigned a0 = wv[4 * c + 0], b0 = wv[4 * c + 2];
          unsigned a1 = wv[4 * c + 1], b1 = wv[4 * c + 3];
          asm("v_permlane32_swap_b32 %0, %1" : "+v"(a0), "+v"(b0));
          asm("v_permlane32_swap_b32 %0, %1" : "+v"(a1), "+v"(b1));
          pa[tt][c][0] = a0;
          pa[tt][c][1] = a1;
          pa[tt][c][2] = b0;
          pa[tt][c][3] = b1;
        }
      }

      // ctx += P @ V : B-operand rows=d from slab[half], s' = tt*32+c*16+hi*8
      __builtin_amdgcn_s_setprio(1);
#pragma unroll
      for (int tt = 0; tt < 2; ++tt)
#pragma unroll
        for (int c = 0; c < 2; ++c) {
          u32x4v pw;
          pw.x = pa[tt][c][0]; pw.y = pa[tt][c][1];
          pw.z = pa[tt][c][2]; pw.w = pa[tt][c][3];
          const bf16x8 aP = __builtin_bit_cast(bf16x8, pw);
#pragma unroll
          for (int dt = 0; dt < 2; ++dt) {
            const bf16x8 bV = *reinterpret_cast<const bf16x8*>(
                &lV[half][(dt * 32 + l31) * 72 + tt * 32 + c * 16 + hi * 8]);
            acc[dt] = __builtin_amdgcn_mfma_f32_32x32x16_bf16(aP, bV, acc[dt], 0, 0, 0);
          }
        }
      __builtin_amdgcn_s_setprio(0);
    }
  }

  const float ltot = lsum + __shfl_xor(lsum, 32);
  if (hi == 0) lsumI[w][l31] = 1.0f / ltot;
  u16* Cp = ctx + (size_t)b * (1024 * 1024) + h * 64;
#pragma unroll
  for (int dt = 0; dt < 2; ++dt)
#pragma unroll
    for (int r = 0; r < 16; ++r) {
      const int q = (r & 3) + 8 * (r >> 2) + 4 * hi;
      const float inv = lsumI[w][q];
      Cp[(q0 + q) * 1024 + dt * 32 + l31] = f2bf(acc[dt][r] * inv);
    }
}

// ---------------- driver ------------------------------------------------------
extern "C" void kernel_launch(void* const* d_in, const int* in_sizes, int n_in,
                              void* d_out, int out_size, void* d_ws, size_t ws_size,
                              hipStream_t stream)
{
  (void)in_sizes; (void)n_in; (void)out_size; (void)ws_size;
  const float* X  = (const float*)d_in[0];
  const float* Y  = (const float*)d_in[1];
  const float* Wq = (const float*)d_in[2];
  const float* bq = (const float*)d_in[3];
  const float* Wk = (const float*)d_in[4];
  const float* bk = (const float*)d_in[5];
  const float* Wv = (const float*)d_in[6];
  const float* bv = (const float*)d_in[7];
  const float* Wg = (const float*)d_in[8];
  const float* bg = (const float*)d_in[9];
  const float* Wb = (const float*)d_in[10];
  const float* bb = (const float*)d_in[11];
  const float* Wo = (const float*)d_in[12];
  const float* bo = (const float*)d_in[13];
  float* out = (float*)d_out;
  char* ws = (char*)d_ws;
  const size_t MB = 1024ull * 1024ull;

  u16* Wqt = (u16*)(ws + 0 * MB);
  u16* Wkt = (u16*)(ws + 2 * MB);
  u16* Wvt = (u16*)(ws + 4 * MB);
  u16* Wcn = (u16*)(ws + 6 * MB);    // Wc = 8*Wg+Wb, non-transposed bf16
  u16* Wot = (u16*)(ws + 8 * MB);
  u16* Wcot = (u16*)(ws + 10 * MB);  // (Wc @ Wo)^T bf16
  u16* Xb = (u16*)(ws + 12 * MB);
  u16* Yb = (u16*)(ws + 28 * MB);
  u16* Qb = (u16*)(ws + 44 * MB);
  u16* Kb = (u16*)(ws + 60 * MB);
  u16* Vt = (u16*)(ws + 76 * MB);
  u16* Cx = (u16*)(ws + 92 * MB);
  float* bqs = (float*)(ws + 108 * MB);
  float* bcs = (float*)(ws + 108 * MB + 4096);
  float* bco = (float*)(ws + 108 * MB + 8192);
  const int NEL = 8 * 1024 * 1024;

  prep_w<<<dim3(32, 32, 5), dim3(32, 8), 0, stream>>>(Wq, Wk, Wv, Wg, Wb, Wo,
                                                      Wqt, Wkt, Wvt, Wcn, Wot);
  prep_b<<<4, 256, 0, stream>>>(bq, bg, bb, bqs, bcs);
  cvt2_bf16<<<2048, 256, 0, stream>>>(X, Xb, Y, Yb, NEL);

  // pass 1: Q1,K1,V1 (+Wcot, +bias_dot)
  gemmp1_k<<<1856, 256, 0, stream>>>(Xb, Yb, Wqt, bqs, Wkt, bk, Wvt, bv,
                                     Qb, Kb, Vt, Wot, Wcn, Wcot, bcs, bo, bco);
  attn_k<<<1024, 256, 0, stream>>>(Qb, Kb, Vt, Cx);
  gemm_k<1><<<512, 256, 0, stream>>>(Cx, Wcot, bco, Yb, out + NEL);   // Y_new

  // pass 2: Q2,K2,V2 adjacent to attn2 (L2-warm K/V)
  gemmp2_k<<<1536, 256, 0, stream>>>(Yb, Wqt, bqs, Qb,
                                     Xb, Wkt, bk, Kb,
                                     Xb, Wvt, bv, Vt);
  attn_k<<<1024, 256, 0, stream>>>(Qb, Kb, Vt, Cx);
  gemm_k<3><<<512, 256, 0, stream>>>(Cx, Wcot, bco, nullptr, out);    // X_new
}

// Round 23
// 281.153 us; speedup vs baseline: 1.2680x; 1.2680x over previous
//
#include <hip/hip_runtime.h>

typedef unsigned short u16;
typedef __bf16 bf16x8 __attribute__((ext_vector_type(8)));
typedef float f32x4 __attribute__((ext_vector_type(4)));
typedef float f32x16 __attribute__((ext_vector_type(16)));
typedef u16 u16x4 __attribute__((ext_vector_type(4)));
typedef unsigned int u32x4v __attribute__((ext_vector_type(4)));

#define LOG2E_OVER_8 0.18033688011112043f

__device__ __forceinline__ u16 f2bf(float f) {
  union { float f; unsigned int u; } x{f};
  unsigned int r = (x.u + 0x7fffu + ((x.u >> 16) & 1u)) >> 16;
  return (u16)r;
}

__device__ __forceinline__ float bf2f(u16 v) {
  union { unsigned int u; float f; } x;
  x.u = ((unsigned int)v) << 16;
  return x.f;
}

__device__ __forceinline__ unsigned cvtpk(float a, float b) {
  unsigned r;
  asm("v_cvt_pk_bf16_f32 %0, %1, %2" : "=v"(r) : "v"(a), "v"(b));
  return r;
}

__device__ __forceinline__ void gld16(const void* g, void* l) {
  __builtin_amdgcn_global_load_lds((const __attribute__((address_space(1))) unsigned int*)g,
                                   (__attribute__((address_space(3))) unsigned int*)l,
                                   16, 0, 0);
}

// ---------------- weight prep -------------------------------------------------
__global__ void prep_w(const float* __restrict__ Wq, const float* __restrict__ Wk,
                       const float* __restrict__ Wv, const float* __restrict__ Wg,
                       const float* __restrict__ Wb, const float* __restrict__ Wo,
                       u16* __restrict__ Wqt, u16* __restrict__ Wkt, u16* __restrict__ Wvt,
                       u16* __restrict__ Wcn, u16* __restrict__ Wot)
{
  __shared__ float tile[32][33];
  const int m = blockIdx.z;
  const int nb = blockIdx.x * 32, kb = blockIdx.y * 32;
  const int tx = threadIdx.x, ty = threadIdx.y;
  const float* src = (m == 0) ? Wq : (m == 1) ? Wk : (m == 2) ? Wv : (m == 3) ? Wg : Wo;
  u16* dst = (m == 0) ? Wqt : (m == 1) ? Wkt : (m == 2) ? Wvt : (m == 3) ? Wcn : Wot;
#pragma unroll
  for (int i = 0; i < 4; ++i) {
    const int k = kb + ty + i * 8;
    float v = src[k * 1024 + nb + tx];
    if (m == 3) v = 8.0f * v + Wb[k * 1024 + nb + tx];
    if (m == 0) v *= LOG2E_OVER_8;
    if (m == 3) dst[k * 1024 + nb + tx] = f2bf(v);   // direct, non-transposed
    else        tile[ty + i * 8][tx] = v;
  }
  __syncthreads();
  if (m != 3) {
#pragma unroll
    for (int i = 0; i < 4; ++i) {
      const int r = ty + i * 8;
      dst[(nb + r) * 1024 + kb + tx] = f2bf(tile[tx][r]);
    }
  }
}

__global__ void prep_b(const float* __restrict__ bq, const float* __restrict__ bg,
                       const float* __restrict__ bb,
                       float* __restrict__ bqs, float* __restrict__ bcs)
{
  const int i = blockIdx.x * 256 + threadIdx.x;
  if (i < 1024) {
    bqs[i] = bq[i] * LOG2E_OVER_8;
    bcs[i] = 8.0f * bg[i] + bb[i];
  }
}

// ---------------- f32 -> bf16 convert (both tensors, one dispatch) -----------
__global__ void cvt2_bf16(const float* __restrict__ in0, u16* __restrict__ out0,
                          const float* __restrict__ in1, u16* __restrict__ out1, int n)
{
  int i = (blockIdx.x * blockDim.x + threadIdx.x) * 4;
  const int stride = gridDim.x * blockDim.x * 4;
  for (; i < n; i += stride) {
    const float4 v0 = *reinterpret_cast<const float4*>(in0 + i);
    u16x4 o0;
    o0.x = f2bf(v0.x); o0.y = f2bf(v0.y); o0.z = f2bf(v0.z); o0.w = f2bf(v0.w);
    *reinterpret_cast<u16x4*>(out0 + i) = o0;
    const float4 v1 = *reinterpret_cast<const float4*>(in1 + i);
    u16x4 o1;
    o1.x = f2bf(v1.x); o1.y = f2bf(v1.y); o1.z = f2bf(v1.z); o1.w = f2bf(v1.w);
    *reinterpret_cast<u16x4*>(out1 + i) = o1;
  }
}

// ---------------- GEMM body (round-14 verified single-buffer, BK=64) ----------
// XOR-swizzled LDS (G21 both-sides, SQ_LDS_BANK_CONFLICT=0 verified).
// EPI: 0 = bf16 out; 1 = fp32 + bf16 out; 2 = bf16 out transposed per head
//      Vt[b][h][d][s]; 3 = fp32 out only; 4 = bf16 out, NO bias.
template<int EPI, int NB>
__device__ __forceinline__ void gemm_body(int bid0, u16* lA, u16* lB,
                                          const u16* __restrict__ A,
                                          const u16* __restrict__ Bt,
                                          const float* __restrict__ bias,
                                          u16* __restrict__ outb, float* __restrict__ outf)
{
  int bid = (bid0 & 7) * NB + (bid0 >> 3);   // XCD-contiguous row bands (grid%8==0)
  const int row0 = (bid >> 3) * 128;
  const int col0 = (bid & 7) * 128;
  const int t = threadIdx.x;
  const int w = t >> 6, lane = t & 63;
  const int l15 = lane & 15, l4 = lane >> 4;
  const int wr = w >> 1, wc = w & 1;
  const int l7 = l15 & 7;

  const u16* gA[4];
  const u16* gB[4];
#pragma unroll
  for (int k2 = 0; k2 < 4; ++k2) {
    const int c = k2 * 256 + t;
    const int r = c >> 3;
    const int sc = ((c & 7) ^ (r & 7)) * 8;
    gA[k2] = A + (row0 + r) * 1024 + sc;
    gB[k2] = Bt + (col0 + r) * 1024 + sc;
  }

  f32x4 acc[4][4] = {};

  for (int kt = 0; kt < 1024; kt += 64) {
#pragma unroll
    for (int k2 = 0; k2 < 4; ++k2) {
      gld16(gA[k2] + kt, lA + (k2 * 256 + w * 64) * 8);
      gld16(gB[k2] + kt, lB + (k2 * 256 + w * 64) * 8);
    }
    __syncthreads();
    bf16x8 aF[4][2], bF[4][2];
#pragma unroll
    for (int m = 0; m < 4; ++m)
#pragma unroll
      for (int ks = 0; ks < 2; ++ks)
        aF[m][ks] = *reinterpret_cast<const bf16x8*>(
            &lA[(wr * 64 + m * 16 + l15) * 64 + ((ks * 4 + l4) ^ l7) * 8]);
#pragma unroll
    for (int n = 0; n < 4; ++n)
#pragma unroll
      for (int ks = 0; ks < 2; ++ks)
        bF[n][ks] = *reinterpret_cast<const bf16x8*>(
            &lB[(wc * 64 + n * 16 + l15) * 64 + ((ks * 4 + l4) ^ l7) * 8]);
#pragma unroll
    for (int m = 0; m < 4; ++m)
#pragma unroll
      for (int n = 0; n < 4; ++n) {
        acc[m][n] = __builtin_amdgcn_mfma_f32_16x16x32_bf16(aF[m][0], bF[n][0], acc[m][n], 0, 0, 0);
        acc[m][n] = __builtin_amdgcn_mfma_f32_16x16x32_bf16(aF[m][1], bF[n][1], acc[m][n], 0, 0, 0);
      }
    __syncthreads();
  }

  float bv[4];
#pragma unroll
  for (int n = 0; n < 4; ++n)
    bv[n] = (EPI == 4) ? 0.0f : bias[col0 + wc * 64 + n * 16 + l15];
#pragma unroll
  for (int m = 0; m < 4; ++m) {
#pragma unroll
    for (int n = 0; n < 4; ++n) {
      const int c = col0 + wc * 64 + n * 16 + l15;
#pragma unroll
      for (int j = 0; j < 4; ++j) {
        const int r = row0 + wr * 64 + m * 16 + l4 * 4 + j;
        const float v = acc[m][n][j] + bv[n];
        if constexpr (EPI == 0 || EPI == 4) {
          outb[r * 1024 + c] = f2bf(v);
        } else if constexpr (EPI == 1) {
          outf[r * 1024 + c] = v;
          outb[r * 1024 + c] = f2bf(v);
        } else if constexpr (EPI == 2) {
          const int bi = r >> 10, s = r & 1023;
          const int h = c >> 6, d = c & 63;
          outb[((bi * 16 + h) * 64 + d) * 1024 + s] = f2bf(v);
        } else {
          outf[r * 1024 + c] = v;
        }
      }
    }
  }
}

// bias job: bco[n] = dot(bcs, Wot-row-n) + bo[n]; 256 blocks, wave per row
__device__ __forceinline__ void bias_body(int bb, const float* __restrict__ bcs,
                                          const u16* __restrict__ Wot,
                                          const float* __restrict__ bo,
                                          float* __restrict__ bco)
{
  const int t = threadIdx.x, w = t >> 6, l = t & 63;
  const int n = bb * 4 + w;
  const u16* row = Wot + n * 1024;
  float a = 0.f;
#pragma unroll
  for (int i = 0; i < 16; ++i) a += bcs[l + 64 * i] * bf2f(row[l + 64 * i]);
#pragma unroll
  for (int d = 1; d < 64; d <<= 1) a += __shfl_xor(a, d);
  if (l == 0) bco[n] = a + bo[n];
}

template<int EPI, int NB = 64>
__global__ __launch_bounds__(256, 2)
void gemm_k(const u16* __restrict__ A, const u16* __restrict__ Bt,
            const float* __restrict__ bias,
            u16* __restrict__ outb, float* __restrict__ outf)
{
  __shared__ u16 lA[128 * 64];
  __shared__ u16 lB[128 * 64];
  gemm_body<EPI, NB>((int)blockIdx.x, lA, lB, A, Bt, bias, outb, outf);
}

// pass-1 mega: Q1(0-511), K1(512-1023), V1(1024-1535), Wcot(1536-1599),
// bias_dot(1600-1855). grid = 1856.
__global__ __launch_bounds__(256, 2)
void gemmp1_k(const u16* __restrict__ Xb, const u16* __restrict__ Yb,
              const u16* __restrict__ Wqt, const float* __restrict__ bqs,
              const u16* __restrict__ Wkt, const float* __restrict__ bk,
              const u16* __restrict__ Wvt, const float* __restrict__ bv,
              u16* __restrict__ Qb, u16* __restrict__ Kb, u16* __restrict__ Vt,
              const u16* __restrict__ Wot, const u16* __restrict__ Wcn,
              u16* __restrict__ Wcot,
              const float* __restrict__ bcs, const float* __restrict__ bo,
              float* __restrict__ bco)
{
  __shared__ u16 lA[128 * 64];
  __shared__ u16 lB[128 * 64];
  const int id = (int)blockIdx.x;
  if (id < 512)       gemm_body<0, 64>(id,        lA, lB, Xb, Wqt, bqs, Qb, nullptr);
  else if (id < 1024) gemm_body<0, 64>(id - 512,  lA, lB, Yb, Wkt, bk, Kb, nullptr);
  else if (id < 1536) gemm_body<2, 64>(id - 1024, lA, lB, Yb, Wvt, bv, Vt, nullptr);
  else if (id < 1600) gemm_body<4, 8>(id - 1536,  lA, lB, Wot, Wcn, nullptr, Wcot, nullptr);
  else                bias_body(id - 1600, bcs, Wot, bo, bco);
}

// pass-2: Q2(0-511), K2(512-1023), V2(1024-1535). grid = 1536.
// K2/V2 stay adjacent to attn2 (producer->consumer L2 warmth is load-bearing).
__global__ __launch_bounds__(256, 2)
void gemmp2_k(const u16* __restrict__ A0, const u16* __restrict__ B0,
              const float* __restrict__ c0, u16* __restrict__ o0,
              const u16* __restrict__ A1, const u16* __restrict__ B1,
              const float* __restrict__ c1, u16* __restrict__ o1,
              const u16* __restrict__ A2, const u16* __restrict__ B2,
              const float* __restrict__ c2, u16* __restrict__ o2)
{
  __shared__ u16 lA[128 * 64];
  __shared__ u16 lB[128 * 64];
  const int id = (int)blockIdx.x;
  if (id < 512)       gemm_body<0, 64>(id,        lA, lB, A0, B0, c0, o0, nullptr);
  else if (id < 1024) gemm_body<0, 64>(id - 512,  lA, lB, A1, B1, c1, o1, nullptr);
  else                gemm_body<2, 64>(id - 1024, lA, lB, A2, B2, c2, o2, nullptr);
}

// ---------------- flash attention v7 (KVBLK=64, verified 47us) ----------------
// no-max softmax (|S| bounded, exp2 in-range; divide by sum at end), swapped
// QK^T 32x32x16, permlane32_swap half-exchange, K/V LDS staging + T14
// async-stage + XCD co-location. KVBLK=128 attempt spilled (VGPR 64,
// WRITE_SIZE 181MB scratch traffic) - reverted.
__global__ __launch_bounds__(256, 4)
void attn_k(const u16* __restrict__ Q, const u16* __restrict__ K,
            const u16* __restrict__ Vt, u16* __restrict__ ctx)
{
  __shared__ u16 lK[64 * 72];
  __shared__ u16 lV[64 * 72];
  __shared__ float lsumI[4][32];
  const int id = (int)blockIdx.x;
  const int xcd = id & 7, o = id >> 3;
  const int pair = xcd * 16 + (o >> 3);   // 16 (b,h) pairs per XCD
  const int qt = o & 7;
  const int b = pair >> 4, h = pair & 15;
  const int t = threadIdx.x, w = t >> 6, lane = t & 63;
  const int l31 = lane & 31, hi = lane >> 5;
  const int q0 = qt * 128 + w * 32;
  const u16* Qp = Q + (size_t)b * (1024 * 1024) + h * 64;
  const u16* Kp = K + (size_t)b * (1024 * 1024) + h * 64;
  const u16* Vp = Vt + (size_t)(b * 16 + h) * (64 * 1024);

  const int r0 = t >> 3, c0 = (t & 7) * 8;

  bf16x8 bQ[4];
#pragma unroll
  for (int ks = 0; ks < 4; ++ks)
    bQ[ks] = *reinterpret_cast<const bf16x8*>(&Qp[(q0 + l31) * 1024 + ks * 16 + hi * 8]);

  f32x16 acc[2] = {};
  float lsum = 0.f;

  bf16x8 sK0, sK1, sV0, sV1;
  sK0 = *reinterpret_cast<const bf16x8*>(&Kp[(r0) * 1024 + c0]);
  sK1 = *reinterpret_cast<const bf16x8*>(&Kp[(r0 + 32) * 1024 + c0]);
  sV0 = *reinterpret_cast<const bf16x8*>(&Vp[r0 * 1024 + c0]);
  sV1 = *reinterpret_cast<const bf16x8*>(&Vp[(r0 + 32) * 1024 + c0]);

  for (int it = 0; it < 16; ++it) {
    const int kv0 = it * 64;
    __syncthreads();
    *reinterpret_cast<bf16x8*>(&lK[r0 * 72 + c0]) = sK0;
    *reinterpret_cast<bf16x8*>(&lK[(r0 + 32) * 72 + c0]) = sK1;
    *reinterpret_cast<bf16x8*>(&lV[r0 * 72 + c0]) = sV0;
    *reinterpret_cast<bf16x8*>(&lV[(r0 + 32) * 72 + c0]) = sV1;
    __syncthreads();
    if (it + 1 < 16) {
      const int nk = kv0 + 64;
      sK0 = *reinterpret_cast<const bf16x8*>(&Kp[(nk + r0) * 1024 + c0]);
      sK1 = *reinterpret_cast<const bf16x8*>(&Kp[(nk + r0 + 32) * 1024 + c0]);
      sV0 = *reinterpret_cast<const bf16x8*>(&Vp[r0 * 1024 + nk + c0]);
      sV1 = *reinterpret_cast<const bf16x8*>(&Vp[(r0 + 32) * 1024 + nk + c0]);
    }

    f32x16 sS[2] = {};
    __builtin_amdgcn_s_setprio(1);
#pragma unroll
    for (int tt = 0; tt < 2; ++tt) {
#pragma unroll
      for (int ks = 0; ks < 4; ++ks) {
        const bf16x8 aK = *reinterpret_cast<const bf16x8*>(
            &lK[(tt * 32 + l31) * 72 + ks * 16 + hi * 8]);
        sS[tt] = __builtin_amdgcn_mfma_f32_32x32x16_bf16(aK, bQ[ks], sS[tt], 0, 0, 0);
      }
    }
    __builtin_amdgcn_s_setprio(0);

    unsigned pa[2][2][4];
#pragma unroll
    for (int tt = 0; tt < 2; ++tt) {
      float p[16];
      float s0 = 0.f, s1 = 0.f, s2 = 0.f, s3 = 0.f;
#pragma unroll
      for (int r = 0; r < 16; r += 4) {
        p[r]     = __builtin_amdgcn_exp2f(sS[tt][r]);
        p[r + 1] = __builtin_amdgcn_exp2f(sS[tt][r + 1]);
        p[r + 2] = __builtin_amdgcn_exp2f(sS[tt][r + 2]);
        p[r + 3] = __builtin_amdgcn_exp2f(sS[tt][r + 3]);
        s0 += p[r]; s1 += p[r + 1]; s2 += p[r + 2]; s3 += p[r + 3];
      }
      lsum += (s0 + s1) + (s2 + s3);
      unsigned wv[8];
#pragma unroll
      for (int i = 0; i < 8; ++i) wv[i] = cvtpk(p[2 * i], p[2 * i + 1]);
#pragma unroll
      for (int c = 0; c < 2; ++c) {
        unsigned a0 = wv[4 * c + 0], b0 = wv[4 * c + 2];
        unsigned a1 = wv[4 * c + 1], b1 = wv[4 * c + 3];
        asm("v_permlane32_swap_b32 %0, %1" : "+v"(a0), "+v"(b0));
        asm("v_permlane32_swap_b32 %0, %1" : "+v"(a1), "+v"(b1));
        pa[tt][c][0] = a0;
        pa[tt][c][1] = a1;
        pa[tt][c][2] = b0;
        pa[tt][c][3] = b1;
      }
    }

    __builtin_amdgcn_s_setprio(1);
#pragma unroll
    for (int tt = 0; tt < 2; ++tt)
#pragma unroll
      for (int c = 0; c < 2; ++c) {
        u32x4v pw;
        pw.x = pa[tt][c][0]; pw.y = pa[tt][c][1];
        pw.z = pa[tt][c][2]; pw.w = pa[tt][c][3];
        const bf16x8 aP = __builtin_bit_cast(bf16x8, pw);
#pragma unroll
        for (int dt = 0; dt < 2; ++dt) {
          const bf16x8 bV = *reinterpret_cast<const bf16x8*>(
              &lV[(dt * 32 + l31) * 72 + tt * 32 + c * 16 + hi * 8]);
          acc[dt] = __builtin_amdgcn_mfma_f32_32x32x16_bf16(aP, bV, acc[dt], 0, 0, 0);
        }
      }
    __builtin_amdgcn_s_setprio(0);
  }

  const float ltot = lsum + __shfl_xor(lsum, 32);
  if (hi == 0) lsumI[w][l31] = 1.0f / ltot;
  u16* Cp = ctx + (size_t)b * (1024 * 1024) + h * 64;
#pragma unroll
  for (int dt = 0; dt < 2; ++dt)
#pragma unroll
    for (int r = 0; r < 16; ++r) {
      const int q = (r & 3) + 8 * (r >> 2) + 4 * hi;
      const float inv = lsumI[w][q];
      Cp[(q0 + q) * 1024 + dt * 32 + l31] = f2bf(acc[dt][r] * inv);
    }
}

// ---------------- driver ------------------------------------------------------
extern "C" void kernel_launch(void* const* d_in, const int* in_sizes, int n_in,
                              void* d_out, int out_size, void* d_ws, size_t ws_size,
                              hipStream_t stream)
{
  (void)in_sizes; (void)n_in; (void)out_size; (void)ws_size;
  const float* X  = (const float*)d_in[0];
  const float* Y  = (const float*)d_in[1];
  const float* Wq = (const float*)d_in[2];
  const float* bq = (const float*)d_in[3];
  const float* Wk = (const float*)d_in[4];
  const float* bk = (const float*)d_in[5];
  const float* Wv = (const float*)d_in[6];
  const float* bv = (const float*)d_in[7];
  const float* Wg = (const float*)d_in[8];
  const float* bg = (const float*)d_in[9];
  const float* Wb = (const float*)d_in[10];
  const float* bb = (const float*)d_in[11];
  const float* Wo = (const float*)d_in[12];
  const float* bo = (const float*)d_in[13];
  float* out = (float*)d_out;
  char* ws = (char*)d_ws;
  const size_t MB = 1024ull * 1024ull;

  u16* Wqt = (u16*)(ws + 0 * MB);
  u16* Wkt = (u16*)(ws + 2 * MB);
  u16* Wvt = (u16*)(ws + 4 * MB);
  u16* Wcn = (u16*)(ws + 6 * MB);    // Wc = 8*Wg+Wb, non-transposed bf16
  u16* Wot = (u16*)(ws + 8 * MB);
  u16* Wcot = (u16*)(ws + 10 * MB);  // (Wc @ Wo)^T bf16
  u16* Xb = (u16*)(ws + 12 * MB);
  u16* Yb = (u16*)(ws + 28 * MB);
  u16* Qb = (u16*)(ws + 44 * MB);
  u16* Kb = (u16*)(ws + 60 * MB);
  u16* Vt = (u16*)(ws + 76 * MB);
  u16* Cx = (u16*)(ws + 92 * MB);
  float* bqs = (float*)(ws + 108 * MB);
  float* bcs = (float*)(ws + 108 * MB + 4096);
  float* bco = (float*)(ws + 108 * MB + 8192);
  const int NEL = 8 * 1024 * 1024;

  prep_w<<<dim3(32, 32, 5), dim3(32, 8), 0, stream>>>(Wq, Wk, Wv, Wg, Wb, Wo,
                                                      Wqt, Wkt, Wvt, Wcn, Wot);
  prep_b<<<4, 256, 0, stream>>>(bq, bg, bb, bqs, bcs);
  cvt2_bf16<<<2048, 256, 0, stream>>>(X, Xb, Y, Yb, NEL);

  // pass 1: Q1,K1,V1 (+Wcot, +bias_dot)
  gemmp1_k<<<1856, 256, 0, stream>>>(Xb, Yb, Wqt, bqs, Wkt, bk, Wvt, bv,
                                     Qb, Kb, Vt, Wot, Wcn, Wcot, bcs, bo, bco);
  attn_k<<<1024, 256, 0, stream>>>(Qb, Kb, Vt, Cx);
  gemm_k<1><<<512, 256, 0, stream>>>(Cx, Wcot, bco, Yb, out + NEL);   // Y_new

  // pass 2: Q2,K2,V2 adjacent to attn2 (L2-warm K/V)
  gemmp2_k<<<1536, 256, 0, stream>>>(Yb, Wqt, bqs, Qb,
                                     Xb, Wkt, bk, Kb,
                                     Xb, Wvt, bv, Vt);
  attn_k<<<1024, 256, 0, stream>>>(Qb, Kb, Vt, Cx);
  gemm_k<3><<<512, 256, 0, stream>>>(Cx, Wcot, bco, nullptr, out);    // X_new
}

// Round 24
// 281.063 us; speedup vs baseline: 1.2684x; 1.0003x over previous
//
#include <hip/hip_runtime.h>

typedef unsigned short u16;
typedef __bf16 bf16x8 __attribute__((ext_vector_type(8)));
typedef float f32x4 __attribute__((ext_vector_type(4)));
typedef float f32x16 __attribute__((ext_vector_type(16)));
typedef u16 u16x4 __attribute__((ext_vector_type(4)));
typedef unsigned int u32x4v __attribute__((ext_vector_type(4)));

#define LOG2E_OVER_8 0.18033688011112043f

__device__ __forceinline__ u16 f2bf(float f) {
  union { float f; unsigned int u; } x{f};
  unsigned int r = (x.u + 0x7fffu + ((x.u >> 16) & 1u)) >> 16;
  return (u16)r;
}

__device__ __forceinline__ float bf2f(u16 v) {
  union { unsigned int u; float f; } x;
  x.u = ((unsigned int)v) << 16;
  return x.f;
}

__device__ __forceinline__ unsigned cvtpk(float a, float b) {
  unsigned r;
  asm("v_cvt_pk_bf16_f32 %0, %1, %2" : "=v"(r) : "v"(a), "v"(b));
  return r;
}

__device__ __forceinline__ void gld16(const void* g, void* l) {
  __builtin_amdgcn_global_load_lds((const __attribute__((address_space(1))) unsigned int*)g,
                                   (__attribute__((address_space(3))) unsigned int*)l,
                                   16, 0, 0);
}

// ---------------- weight prep -------------------------------------------------
__global__ void prep_w(const float* __restrict__ Wq, const float* __restrict__ Wk,
                       const float* __restrict__ Wv, const float* __restrict__ Wg,
                       const float* __restrict__ Wb, const float* __restrict__ Wo,
                       u16* __restrict__ Wqt, u16* __restrict__ Wkt, u16* __restrict__ Wvt,
                       u16* __restrict__ Wcn, u16* __restrict__ Wot)
{
  __shared__ float tile[32][33];
  const int m = blockIdx.z;
  const int nb = blockIdx.x * 32, kb = blockIdx.y * 32;
  const int tx = threadIdx.x, ty = threadIdx.y;
  const float* src = (m == 0) ? Wq : (m == 1) ? Wk : (m == 2) ? Wv : (m == 3) ? Wg : Wo;
  u16* dst = (m == 0) ? Wqt : (m == 1) ? Wkt : (m == 2) ? Wvt : (m == 3) ? Wcn : Wot;
#pragma unroll
  for (int i = 0; i < 4; ++i) {
    const int k = kb + ty + i * 8;
    float v = src[k * 1024 + nb + tx];
    if (m == 3) v = 8.0f * v + Wb[k * 1024 + nb + tx];
    if (m == 0) v *= LOG2E_OVER_8;
    if (m == 3) dst[k * 1024 + nb + tx] = f2bf(v);   // direct, non-transposed
    else        tile[ty + i * 8][tx] = v;
  }
  __syncthreads();
  if (m != 3) {
#pragma unroll
    for (int i = 0; i < 4; ++i) {
      const int r = ty + i * 8;
      dst[(nb + r) * 1024 + kb + tx] = f2bf(tile[tx][r]);
    }
  }
}

__global__ void prep_b(const float* __restrict__ bq, const float* __restrict__ bg,
                       const float* __restrict__ bb,
                       float* __restrict__ bqs, float* __restrict__ bcs)
{
  const int i = blockIdx.x * 256 + threadIdx.x;
  if (i < 1024) {
    bqs[i] = bq[i] * LOG2E_OVER_8;
    bcs[i] = 8.0f * bg[i] + bb[i];
  }
}

// ---------------- f32 -> bf16 convert (both tensors, one dispatch) -----------
__global__ void cvt2_bf16(const float* __restrict__ in0, u16* __restrict__ out0,
                          const float* __restrict__ in1, u16* __restrict__ out1, int n)
{
  int i = (blockIdx.x * blockDim.x + threadIdx.x) * 4;
  const int stride = gridDim.x * blockDim.x * 4;
  for (; i < n; i += stride) {
    const float4 v0 = *reinterpret_cast<const float4*>(in0 + i);
    u16x4 o0;
    o0.x = f2bf(v0.x); o0.y = f2bf(v0.y); o0.z = f2bf(v0.z); o0.w = f2bf(v0.w);
    *reinterpret_cast<u16x4*>(out0 + i) = o0;
    const float4 v1 = *reinterpret_cast<const float4*>(in1 + i);
    u16x4 o1;
    o1.x = f2bf(v1.x); o1.y = f2bf(v1.y); o1.z = f2bf(v1.z); o1.w = f2bf(v1.w);
    *reinterpret_cast<u16x4*>(out1 + i) = o1;
  }
}

// ---------------- GEMM body (round-14 verified single-buffer, BK=64) ----------
// XOR-swizzled LDS (G21 both-sides, SQ_LDS_BANK_CONFLICT=0 verified).
// EPI: 0 = bf16 out; 1 = fp32 + bf16 out; 2 = bf16 out transposed per head
//      Vt[b][h][d][s]; 3 = fp32 out only; 4 = bf16 out, NO bias.
template<int EPI, int NB>
__device__ __forceinline__ void gemm_body(int bid0, u16* lA, u16* lB,
                                          const u16* __restrict__ A,
                                          const u16* __restrict__ Bt,
                                          const float* __restrict__ bias,
                                          u16* __restrict__ outb, float* __restrict__ outf)
{
  int bid = (bid0 & 7) * NB + (bid0 >> 3);   // XCD-contiguous row bands (grid%8==0)
  const int row0 = (bid >> 3) * 128;
  const int col0 = (bid & 7) * 128;
  const int t = threadIdx.x;
  const int w = t >> 6, lane = t & 63;
  const int l15 = lane & 15, l4 = lane >> 4;
  const int wr = w >> 1, wc = w & 1;
  const int l7 = l15 & 7;

  const u16* gA[4];
  const u16* gB[4];
#pragma unroll
  for (int k2 = 0; k2 < 4; ++k2) {
    const int c = k2 * 256 + t;
    const int r = c >> 3;
    const int sc = ((c & 7) ^ (r & 7)) * 8;
    gA[k2] = A + (row0 + r) * 1024 + sc;
    gB[k2] = Bt + (col0 + r) * 1024 + sc;
  }

  f32x4 acc[4][4] = {};

  for (int kt = 0; kt < 1024; kt += 64) {
#pragma unroll
    for (int k2 = 0; k2 < 4; ++k2) {
      gld16(gA[k2] + kt, lA + (k2 * 256 + w * 64) * 8);
      gld16(gB[k2] + kt, lB + (k2 * 256 + w * 64) * 8);
    }
    __syncthreads();
    bf16x8 aF[4][2], bF[4][2];
#pragma unroll
    for (int m = 0; m < 4; ++m)
#pragma unroll
      for (int ks = 0; ks < 2; ++ks)
        aF[m][ks] = *reinterpret_cast<const bf16x8*>(
            &lA[(wr * 64 + m * 16 + l15) * 64 + ((ks * 4 + l4) ^ l7) * 8]);
#pragma unroll
    for (int n = 0; n < 4; ++n)
#pragma unroll
      for (int ks = 0; ks < 2; ++ks)
        bF[n][ks] = *reinterpret_cast<const bf16x8*>(
            &lB[(wc * 64 + n * 16 + l15) * 64 + ((ks * 4 + l4) ^ l7) * 8]);
#pragma unroll
    for (int m = 0; m < 4; ++m)
#pragma unroll
      for (int n = 0; n < 4; ++n) {
        acc[m][n] = __builtin_amdgcn_mfma_f32_16x16x32_bf16(aF[m][0], bF[n][0], acc[m][n], 0, 0, 0);
        acc[m][n] = __builtin_amdgcn_mfma_f32_16x16x32_bf16(aF[m][1], bF[n][1], acc[m][n], 0, 0, 0);
      }
    __syncthreads();
  }

  float bv[4];
#pragma unroll
  for (int n = 0; n < 4; ++n)
    bv[n] = (EPI == 4) ? 0.0f : bias[col0 + wc * 64 + n * 16 + l15];
#pragma unroll
  for (int m = 0; m < 4; ++m) {
#pragma unroll
    for (int n = 0; n < 4; ++n) {
      const int c = col0 + wc * 64 + n * 16 + l15;
#pragma unroll
      for (int j = 0; j < 4; ++j) {
        const int r = row0 + wr * 64 + m * 16 + l4 * 4 + j;
        const float v = acc[m][n][j] + bv[n];
        if constexpr (EPI == 0 || EPI == 4) {
          outb[r * 1024 + c] = f2bf(v);
        } else if constexpr (EPI == 1) {
          outf[r * 1024 + c] = v;
          outb[r * 1024 + c] = f2bf(v);
        } else if constexpr (EPI == 2) {
          const int bi = r >> 10, s = r & 1023;
          const int h = c >> 6, d = c & 63;
          outb[((bi * 16 + h) * 64 + d) * 1024 + s] = f2bf(v);
        } else {
          outf[r * 1024 + c] = v;
        }
      }
    }
  }
}

// bias job: bco[n] = dot(bcs, Wot-row-n) + bo[n]; 256 blocks, wave per row
__device__ __forceinline__ void bias_body(int bb, const float* __restrict__ bcs,
                                          const u16* __restrict__ Wot,
                                          const float* __restrict__ bo,
                                          float* __restrict__ bco)
{
  const int t = threadIdx.x, w = t >> 6, l = t & 63;
  const int n = bb * 4 + w;
  const u16* row = Wot + n * 1024;
  float a = 0.f;
#pragma unroll
  for (int i = 0; i < 16; ++i) a += bcs[l + 64 * i] * bf2f(row[l + 64 * i]);
#pragma unroll
  for (int d = 1; d < 64; d <<= 1) a += __shfl_xor(a, d);
  if (l == 0) bco[n] = a + bo[n];
}

template<int EPI, int NB = 64>
__global__ __launch_bounds__(256, 2)
void gemm_k(const u16* __restrict__ A, const u16* __restrict__ Bt,
            const float* __restrict__ bias,
            u16* __restrict__ outb, float* __restrict__ outf)
{
  __shared__ u16 lA[128 * 64];
  __shared__ u16 lB[128 * 64];
  gemm_body<EPI, NB>((int)blockIdx.x, lA, lB, A, Bt, bias, outb, outf);
}

// pass-1 mega: Q1(0-511), K1(512-1023), V1(1024-1535), Wcot(1536-1599),
// bias_dot(1600-1855). grid = 1856.
__global__ __launch_bounds__(256, 2)
void gemmp1_k(const u16* __restrict__ Xb, const u16* __restrict__ Yb,
              const u16* __restrict__ Wqt, const float* __restrict__ bqs,
              const u16* __restrict__ Wkt, const float* __restrict__ bk,
              const u16* __restrict__ Wvt, const float* __restrict__ bv,
              u16* __restrict__ Qb, u16* __restrict__ Kb, u16* __restrict__ Vt,
              const u16* __restrict__ Wot, const u16* __restrict__ Wcn,
              u16* __restrict__ Wcot,
              const float* __restrict__ bcs, const float* __restrict__ bo,
              float* __restrict__ bco)
{
  __shared__ u16 lA[128 * 64];
  __shared__ u16 lB[128 * 64];
  const int id = (int)blockIdx.x;
  if (id < 512)       gemm_body<0, 64>(id,        lA, lB, Xb, Wqt, bqs, Qb, nullptr);
  else if (id < 1024) gemm_body<0, 64>(id - 512,  lA, lB, Yb, Wkt, bk, Kb, nullptr);
  else if (id < 1536) gemm_body<2, 64>(id - 1024, lA, lB, Yb, Wvt, bv, Vt, nullptr);
  else if (id < 1600) gemm_body<4, 8>(id - 1536,  lA, lB, Wot, Wcn, nullptr, Wcot, nullptr);
  else                bias_body(id - 1600, bcs, Wot, bo, bco);
}

// pass-2: Q2(0-511), K2(512-1023), V2(1024-1535). grid = 1536.
// K2/V2 stay adjacent to attn2 (producer->consumer L2 warmth is load-bearing).
__global__ __launch_bounds__(256, 2)
void gemmp2_k(const u16* __restrict__ A0, const u16* __restrict__ B0,
              const float* __restrict__ c0, u16* __restrict__ o0,
              const u16* __restrict__ A1, const u16* __restrict__ B1,
              const float* __restrict__ c1, u16* __restrict__ o1,
              const u16* __restrict__ A2, const u16* __restrict__ B2,
              const float* __restrict__ c2, u16* __restrict__ o2)
{
  __shared__ u16 lA[128 * 64];
  __shared__ u16 lB[128 * 64];
  const int id = (int)blockIdx.x;
  if (id < 512)       gemm_body<0, 64>(id,        lA, lB, A0, B0, c0, o0, nullptr);
  else if (id < 1024) gemm_body<0, 64>(id - 512,  lA, lB, A1, B1, c1, o1, nullptr);
  else                gemm_body<2, 64>(id - 1024, lA, lB, A2, B2, c2, o2, nullptr);
}

// ---------------- flash attention v9: gld16 staging + dbuf linear LDS ---------
// v7 math (no-max softmax, swapped QK^T 32x32x16, permlane32_swap) but K/V
// staged via global_load_lds into LINEAR [64][64] double-buffered tiles with
// the GEMM's proven G21 both-sides XOR swizzle (source col-chunk ^= row&7,
// reads apply same XOR; conflict-free verified on the GEMM path). Removes the
// VGPR round-trip (8 loads + 8 ds_write/iter, -32 staging regs); prefetch for
// tile it+1 issued into buf^1 BEFORE compute -> latency hides under compute;
// one barrier/iter drains it. LDS 33KB -> 4 blocks/CU unchanged.
__global__ __launch_bounds__(256, 4)
void attn_k(const u16* __restrict__ Q, const u16* __restrict__ K,
            const u16* __restrict__ Vt, u16* __restrict__ ctx)
{
  __shared__ u16 lK[2][64 * 64];
  __shared__ u16 lV[2][64 * 64];
  __shared__ float lsumI[4][32];
  const int id = (int)blockIdx.x;
  const int xcd = id & 7, o = id >> 3;
  const int pair = xcd * 16 + (o >> 3);   // 16 (b,h) pairs per XCD
  const int qt = o & 7;
  const int b = pair >> 4, h = pair & 15;
  const int t = threadIdx.x, w = t >> 6, lane = t & 63;
  const int l31 = lane & 31, hi = lane >> 5;
  const int q0 = qt * 128 + w * 32;
  const u16* Qp = Q + (size_t)b * (1024 * 1024) + h * 64;
  const u16* Kp = K + (size_t)b * (1024 * 1024) + h * 64;
  const u16* Vp = Vt + (size_t)(b * 16 + h) * (64 * 1024);

  // staging: thread t owns 16B-chunks t and 256+t of each 64x64 tile.
  // chunk c: row=c>>3, col-chunk=c&7; SOURCE col pre-swizzled by row&7
  // ((r0+32)&7 == r0&7, so one swizzle serves both rows).
  const int r0 = t >> 3;
  const int scA = ((t & 7) ^ (r0 & 7)) * 8;   // u16 units
  const int l7r = l31 & 7;                    // read-side XOR key (row&7)

  bf16x8 bQ[4];
#pragma unroll
  for (int ks = 0; ks < 4; ++ks)
    bQ[ks] = *reinterpret_cast<const bf16x8*>(&Qp[(q0 + l31) * 1024 + ks * 16 + hi * 8]);

  f32x16 acc[2] = {};
  float lsum = 0.f;

  auto STAGE = [&](int buf, int kv) {
    gld16(Kp + (size_t)(kv + r0) * 1024 + scA,        &lK[buf][(w * 64) * 8]);
    gld16(Kp + (size_t)(kv + r0 + 32) * 1024 + scA,   &lK[buf][(256 + w * 64) * 8]);
    gld16(Vp + (size_t)r0 * 1024 + kv + scA,          &lV[buf][(w * 64) * 8]);
    gld16(Vp + (size_t)(r0 + 32) * 1024 + kv + scA,   &lV[buf][(256 + w * 64) * 8]);
  };

  STAGE(0, 0);
  __syncthreads();   // prologue loads drained

  for (int it = 0; it < 16; ++it) {
    const int cur = it & 1;
    if (it + 1 < 16) STAGE(cur ^ 1, (it + 1) * 64);   // in flight under compute

    f32x16 sS[2] = {};
    __builtin_amdgcn_s_setprio(1);
#pragma unroll
    for (int tt = 0; tt < 2; ++tt) {
#pragma unroll
      for (int ks = 0; ks < 4; ++ks) {
        const bf16x8 aK = *reinterpret_cast<const bf16x8*>(
            &lK[cur][(tt * 32 + l31) * 64 + ((2 * ks + hi) ^ l7r) * 8]);
        sS[tt] = __builtin_amdgcn_mfma_f32_32x32x16_bf16(aK, bQ[ks], sS[tt], 0, 0, 0);
      }
    }
    __builtin_amdgcn_s_setprio(0);

    unsigned pa[2][2][4];
#pragma unroll
    for (int tt = 0; tt < 2; ++tt) {
      float p[16];
      float s0 = 0.f, s1 = 0.f, s2 = 0.f, s3 = 0.f;
#pragma unroll
      for (int r = 0; r < 16; r += 4) {
        p[r]     = __builtin_amdgcn_exp2f(sS[tt][r]);
        p[r + 1] = __builtin_amdgcn_exp2f(sS[tt][r + 1]);
        p[r + 2] = __builtin_amdgcn_exp2f(sS[tt][r + 2]);
        p[r + 3] = __builtin_amdgcn_exp2f(sS[tt][r + 3]);
        s0 += p[r]; s1 += p[r + 1]; s2 += p[r + 2]; s3 += p[r + 3];
      }
      lsum += (s0 + s1) + (s2 + s3);
      unsigned wv[8];
#pragma unroll
      for (int i = 0; i < 8; ++i) wv[i] = cvtpk(p[2 * i], p[2 * i + 1]);
#pragma unroll
      for (int c = 0; c < 2; ++c) {
        unsigned a0 = wv[4 * c + 0], b0 = wv[4 * c + 2];
        unsigned a1 = wv[4 * c + 1], b1 = wv[4 * c + 3];
        asm("v_permlane32_swap_b32 %0, %1" : "+v"(a0), "+v"(b0));
        asm("v_permlane32_swap_b32 %0, %1" : "+v"(a1), "+v"(b1));
        pa[tt][c][0] = a0;
        pa[tt][c][1] = a1;
        pa[tt][c][2] = b0;
        pa[tt][c][3] = b1;
      }
    }

    __builtin_amdgcn_s_setprio(1);
#pragma unroll
    for (int tt = 0; tt < 2; ++tt)
#pragma unroll
      for (int c = 0; c < 2; ++c) {
        u32x4v pw;
        pw.x = pa[tt][c][0]; pw.y = pa[tt][c][1];
        pw.z = pa[tt][c][2]; pw.w = pa[tt][c][3];
        const bf16x8 aP = __builtin_bit_cast(bf16x8, pw);
#pragma unroll
        for (int dt = 0; dt < 2; ++dt) {
          const bf16x8 bV = *reinterpret_cast<const bf16x8*>(
              &lV[cur][(dt * 32 + l31) * 64 + ((4 * tt + 2 * c + hi) ^ l7r) * 8]);
          acc[dt] = __builtin_amdgcn_mfma_f32_32x32x16_bf16(aP, bV, acc[dt], 0, 0, 0);
        }
      }
    __builtin_amdgcn_s_setprio(0);
    __syncthreads();   // drains prefetch vmcnt; all waves done reading cur
  }

  const float ltot = lsum + __shfl_xor(lsum, 32);
  if (hi == 0) lsumI[w][l31] = 1.0f / ltot;
  u16* Cp = ctx + (size_t)b * (1024 * 1024) + h * 64;
#pragma unroll
  for (int dt = 0; dt < 2; ++dt)
#pragma unroll
    for (int r = 0; r < 16; ++r) {
      const int q = (r & 3) + 8 * (r >> 2) + 4 * hi;
      const float inv = lsumI[w][q];
      Cp[(q0 + q) * 1024 + dt * 32 + l31] = f2bf(acc[dt][r] * inv);
    }
}

// ---------------- driver ------------------------------------------------------
extern "C" void kernel_launch(void* const* d_in, const int* in_sizes, int n_in,
                              void* d_out, int out_size, void* d_ws, size_t ws_size,
                              hipStream_t stream)
{
  (void)in_sizes; (void)n_in; (void)out_size; (void)ws_size;
  const float* X  = (const float*)d_in[0];
  const float* Y  = (const float*)d_in[1];
  const float* Wq = (const float*)d_in[2];
  const float* bq = (const float*)d_in[3];
  const float* Wk = (const float*)d_in[4];
  const float* bk = (const float*)d_in[5];
  const float* Wv = (const float*)d_in[6];
  const float* bv = (const float*)d_in[7];
  const float* Wg = (const float*)d_in[8];
  const float* bg = (const float*)d_in[9];
  const float* Wb = (const float*)d_in[10];
  const float* bb = (const float*)d_in[11];
  const float* Wo = (const float*)d_in[12];
  const float* bo = (const float*)d_in[13];
  float* out = (float*)d_out;
  char* ws = (char*)d_ws;
  const size_t MB = 1024ull * 1024ull;

  u16* Wqt = (u16*)(ws + 0 * MB);
  u16* Wkt = (u16*)(ws + 2 * MB);
  u16* Wvt = (u16*)(ws + 4 * MB);
  u16* Wcn = (u16*)(ws + 6 * MB);    // Wc = 8*Wg+Wb, non-transposed bf16
  u16* Wot = (u16*)(ws + 8 * MB);
  u16* Wcot = (u16*)(ws + 10 * MB);  // (Wc @ Wo)^T bf16
  u16* Xb = (u16*)(ws + 12 * MB);
  u16* Yb = (u16*)(ws + 28 * MB);
  u16* Qb = (u16*)(ws + 44 * MB);
  u16* Kb = (u16*)(ws + 60 * MB);
  u16* Vt = (u16*)(ws + 76 * MB);
  u16* Cx = (u16*)(ws + 92 * MB);
  float* bqs = (float*)(ws + 108 * MB);
  float* bcs = (float*)(ws + 108 * MB + 4096);
  float* bco = (float*)(ws + 108 * MB + 8192);
  const int NEL = 8 * 1024 * 1024;

  prep_w<<<dim3(32, 32, 5), dim3(32, 8), 0, stream>>>(Wq, Wk, Wv, Wg, Wb, Wo,
                                                      Wqt, Wkt, Wvt, Wcn, Wot);
  prep_b<<<4, 256, 0, stream>>>(bq, bg, bb, bqs, bcs);
  cvt2_bf16<<<2048, 256, 0, stream>>>(X, Xb, Y, Yb, NEL);

  // pass 1: Q1,K1,V1 (+Wcot, +bias_dot)
  gemmp1_k<<<1856, 256, 0, stream>>>(Xb, Yb, Wqt, bqs, Wkt, bk, Wvt, bv,
                                     Qb, Kb, Vt, Wot, Wcn, Wcot, bcs, bo, bco);
  attn_k<<<1024, 256, 0, stream>>>(Qb, Kb, Vt, Cx);
  gemm_k<1><<<512, 256, 0, stream>>>(Cx, Wcot, bco, Yb, out + NEL);   // Y_new

  // pass 2: Q2,K2,V2 adjacent to attn2 (L2-warm K/V)
  gemmp2_k<<<1536, 256, 0, stream>>>(Yb, Wqt, bqs, Qb,
                                     Xb, Wkt, bk, Kb,
                                     Xb, Wvt, bv, Vt);
  attn_k<<<1024, 256, 0, stream>>>(Qb, Kb, Vt, Cx);
  gemm_k<3><<<512, 256, 0, stream>>>(Cx, Wcot, bco, nullptr, out);    // X_new
}